// Round 8
// baseline (129.468 us; speedup 1.0000x reference)
//
#include <hip/hip_runtime.h>
#include <hip/hip_bf16.h>

typedef unsigned short u16;
typedef __attribute__((ext_vector_type(8))) short bf16x8;
typedef __attribute__((ext_vector_type(4))) float f32x4;

typedef const __attribute__((address_space(1))) void gvoid_t;
typedef __attribute__((address_space(3))) void lvoid_t;

__device__ __forceinline__ void gload_lds16(const void* g, void* l) {
  __builtin_amdgcn_global_load_lds((gvoid_t*)g, (lvoid_t*)l, 16, 0, 0);
}

__device__ __forceinline__ u16 f2bf(float f) {
  union { float f; unsigned u; } a;
  a.f = f;
  unsigned r = (a.u + 0x7FFFu + ((a.u >> 16) & 1u)) >> 16;  // RN-even
  return (u16)r;
}

// ---------------------------------------------------------------------------
// Prep: fp32 -> bf16 copies of x and y, plus per-row sum of squares.
// ---------------------------------------------------------------------------
__global__ __launch_bounds__(128) void rbf_prep(
    const float* __restrict__ x, const float* __restrict__ y,
    u16* __restrict__ xb, u16* __restrict__ yb,
    float* __restrict__ xsq, float* __restrict__ ysq,
    int N, int M, int D) {
  int row = blockIdx.x;
  const float* src;
  u16* dst;
  float* sq;
  if (row < N) {
    src = x + (size_t)row * D;
    dst = xb + (size_t)row * D;
    sq = xsq + row;
  } else {
    int r = row - N;
    src = y + (size_t)r * D;
    dst = yb + (size_t)r * D;
    sq = ysq + r;
  }
  int t = threadIdx.x;
  float4 v = reinterpret_cast<const float4*>(src)[t];
  float s = v.x * v.x + v.y * v.y + v.z * v.z + v.w * v.w;
  ushort4 o;
  o.x = f2bf(v.x);
  o.y = f2bf(v.y);
  o.z = f2bf(v.z);
  o.w = f2bf(v.w);
  reinterpret_cast<ushort4*>(dst)[t] = o;
  #pragma unroll
  for (int off = 32; off > 0; off >>= 1) s += __shfl_down(s, off, 64);
  __shared__ float red[2];
  if ((t & 63) == 0) red[t >> 6] = s;
  __syncthreads();
  if (t == 0) sq[0] = red[0] + red[1];
}

// ---------------------------------------------------------------------------
// Faithful m201-style 8-phase GEMM + RBF epilogue.
// 256x256 tile, BK=64, 512 threads = 8 waves (2M x 4N), per-wave out 128x64.
// LDS: [2 dbuf][4 halves: A0,A1,B0,B1][128x64] bf16 = 128 KiB.
// Per K-tile = 4 phases; each phase: {ds_read quadrant subtile | stage ONE
// half (2 gload_lds) | barrier | lgkmcnt(0) | setprio(1) 16 MFMA setprio(0)
// | barrier}. Tile t's 8 loads are issued across tile t-1's phases; at t's
// pre-phase: issue t+1's first half, then counted vmcnt(2) (never 0
// mid-loop) + barrier. WAR-safe: all reads of a buffer retire at that
// tile's phase-2 lgkmcnt(0)+barrier, before the next tile re-stages it.
// Swizzle (both-sides involution): stored chunk p holds logical chunk
// p ^ (row&7); reads use chunk (kk*4+fq) ^ (fr&7)  ->  <=2-way conflicts.
// Swapped MFMA operands: D[j][i] -> per-thread 4 consecutive out cols ->
// float4 stores. exp2-fused epilogue.
// ---------------------------------------------------------------------------
#define BM 256
#define BN 256
#define BK 64

__global__ __launch_bounds__(512, 2) void rbf_gemm(
    const u16* __restrict__ xb, const u16* __restrict__ yb,
    const float* __restrict__ xsq, const float* __restrict__ ysq,
    const float* __restrict__ gptr, float* __restrict__ out,
    int N, int M, int D) {
  __shared__ u16 lds[2][4][128 * 64];  // 128 KiB

  int bid = blockIdx.x;
  int nbr = N / BM, nbc = M / BN;
  int trow, tcol;
  if (nbr == 32 && nbc == 32) {
    // XCD (bid&7) owns an 8x16-tile region; column-major inside.
    int xcd = bid & 7;
    int s = bid >> 3;
    trow = ((xcd >> 1) << 3) + (s & 7);
    tcol = ((xcd & 1) << 4) + (s >> 3);
  } else {
    int cpx = gridDim.x >> 3;
    int swz = (bid & 7) * cpx + (bid >> 3);
    trow = swz / nbc;
    tcol = swz % nbc;
  }
  int brow = trow * BM;
  int bcol = tcol * BN;

  int tid = threadIdx.x;
  int w = tid >> 6;     // wave 0..7
  int lane = tid & 63;
  int wm = w >> 2;      // 0..1 : which 128-row half of A this wave computes
  int wn = w & 3;       // 0..3 : which 64-col quarter
  int fr = lane & 15;
  int fq = lane >> 4;

  // fragment read chunk offsets (elems): chunk (kk*4+fq) ^ (fr&7)
  int cx0 = ((fq) ^ (fr & 7)) * 8;
  int cx1 = ((4 + fq) ^ (fr & 7)) * 8;
  int browB = (wn & 1) * 64;  // row base within this wave's B-half

  // staging: all 512 threads stage one 128x64 half with 2 gloads each.
  // lane l of wave w covers rows {w*8 + (l>>3), +64}, stored chunk l&7,
  // logical (source) chunk (l&7)^(l>>3)  [row&7 == l>>3].
  int sro = w * 8 + (lane >> 3);
  int sch = ((lane & 7) ^ (lane >> 3)) * 8;

  auto stage_half = [&](int kt, int bufb, int h) {
    const u16* base = (h < 2) ? xb + (size_t)(brow + (h & 1) * 128) * D
                              : yb + (size_t)(bcol + (h & 1) * 128) * D;
    const u16* src = base + (size_t)sro * D + kt * 64 + sch;
    u16* dst = &lds[bufb][h][w * 512];  // wave-uniform; HW adds lane*16B
    gload_lds16(src, dst);
    gload_lds16(src + (size_t)64 * D, dst + 4096);
  };

  f32x4 acc[8][4];
  #pragma unroll
  for (int m = 0; m < 8; ++m)
    #pragma unroll
    for (int n = 0; n < 4; ++n)
      acc[m][n] = (f32x4){0.f, 0.f, 0.f, 0.f};

#define QUAD(MS, NS, AF, BF)                                                   \
  {                                                                            \
    __builtin_amdgcn_s_setprio(1);                                             \
    _Pragma("unroll") for (int mi = 0; mi < 4; ++mi)                           \
      _Pragma("unroll") for (int ni = 0; ni < 2; ++ni) {                       \
        acc[MS + mi][NS + ni] = __builtin_amdgcn_mfma_f32_16x16x32_bf16(       \
            BF[ni][0], AF[mi][0], acc[MS + mi][NS + ni], 0, 0, 0);             \
        acc[MS + mi][NS + ni] = __builtin_amdgcn_mfma_f32_16x16x32_bf16(       \
            BF[ni][1], AF[mi][1], acc[MS + mi][NS + ni], 0, 0, 0);             \
      }                                                                        \
    __builtin_amdgcn_s_setprio(0);                                             \
  }

  int nkt = D >> 6;  // 8
  // prologue: stage all 4 halves of tile 0 into buf 0 (8 loads)
  stage_half(0, 0, 0);
  stage_half(0, 0, 2);
  stage_half(0, 0, 1);
  stage_half(0, 0, 3);

  for (int t = 0; t < nkt; ++t) {
    int b = t & 1;
    // ---- pre-phase: issue t+1 half0, force t's 8 loads done ----
    if (t + 1 < nkt) {
      stage_half(t + 1, b ^ 1, 0);
      asm volatile("s_waitcnt vmcnt(2)" ::: "memory");
    } else {
      asm volatile("s_waitcnt vmcnt(0)" ::: "memory");
    }
    __builtin_amdgcn_sched_barrier(0);
    __builtin_amdgcn_s_barrier();
    __builtin_amdgcn_sched_barrier(0);

    const u16* A = &lds[b][wm][0];
    const u16* Bp = &lds[b][2 + (wn >> 1)][0];

    bf16x8 af[4][2], bf0[2][2], bf1[2][2];

    // ---- phase 0: quadrant (M0-3, N0-1); read af(MH0)+bf0; stage h2 ----
    #pragma unroll
    for (int mi = 0; mi < 4; ++mi) {
      af[mi][0] = *(const bf16x8*)&A[(mi * 16 + fr) * 64 + cx0];
      af[mi][1] = *(const bf16x8*)&A[(mi * 16 + fr) * 64 + cx1];
    }
    #pragma unroll
    for (int ni = 0; ni < 2; ++ni) {
      bf0[ni][0] = *(const bf16x8*)&Bp[(browB + ni * 16 + fr) * 64 + cx0];
      bf0[ni][1] = *(const bf16x8*)&Bp[(browB + ni * 16 + fr) * 64 + cx1];
    }
    if (t + 1 < nkt) stage_half(t + 1, b ^ 1, 2);
    __builtin_amdgcn_s_barrier();
    asm volatile("s_waitcnt lgkmcnt(0)" ::: "memory");
    __builtin_amdgcn_sched_barrier(0);
    QUAD(0, 0, af, bf0);
    __builtin_amdgcn_s_barrier();

    // ---- phase 1: quadrant (M0-3, N2-3); read bf1; stage h1 ----
    #pragma unroll
    for (int ni = 0; ni < 2; ++ni) {
      bf1[ni][0] = *(const bf16x8*)&Bp[(browB + 32 + ni * 16 + fr) * 64 + cx0];
      bf1[ni][1] = *(const bf16x8*)&Bp[(browB + 32 + ni * 16 + fr) * 64 + cx1];
    }
    if (t + 1 < nkt) stage_half(t + 1, b ^ 1, 1);
    __builtin_amdgcn_s_barrier();
    asm volatile("s_waitcnt lgkmcnt(0)" ::: "memory");
    __builtin_amdgcn_sched_barrier(0);
    QUAD(0, 2, af, bf1);
    __builtin_amdgcn_s_barrier();

    // ---- phase 2: quadrant (M4-7, N2-3); read af(MH1); stage h3 ----
    #pragma unroll
    for (int mi = 0; mi < 4; ++mi) {
      af[mi][0] = *(const bf16x8*)&A[((mi + 4) * 16 + fr) * 64 + cx0];
      af[mi][1] = *(const bf16x8*)&A[((mi + 4) * 16 + fr) * 64 + cx1];
    }
    if (t + 1 < nkt) stage_half(t + 1, b ^ 1, 3);
    __builtin_amdgcn_s_barrier();
    asm volatile("s_waitcnt lgkmcnt(0)" ::: "memory");
    __builtin_amdgcn_sched_barrier(0);
    QUAD(4, 2, af, bf1);
    __builtin_amdgcn_s_barrier();

    // ---- phase 3: quadrant (M4-7, N0-1); no reads, no stage ----
    QUAD(4, 0, af, bf0);
  }
#undef QUAD

  // Epilogue: out = exp2(2*gl2*acc - gl2*|x|^2 - gl2*|y|^2), clamped <= 2^0.
  // Swapped layout: i = fr (A-row), j = fq*4 + r (B-row) -> float4 stores.
  float gl2 = gptr[0] * 1.44269504088896f;  // gamma * log2(e)
  float m2gl2 = 2.0f * gl2;
  float4 gys[4];
  #pragma unroll
  for (int n = 0; n < 4; ++n) {
    float4 t4 = *reinterpret_cast<const float4*>(
        &ysq[bcol + wn * 64 + n * 16 + fq * 4]);
    gys[n].x = gl2 * t4.x;
    gys[n].y = gl2 * t4.y;
    gys[n].z = gl2 * t4.z;
    gys[n].w = gl2 * t4.w;
  }
  #pragma unroll
  for (int m = 0; m < 8; ++m) {
    int i = brow + wm * 128 + m * 16 + fr;
    float gxs = gl2 * xsq[i];
    size_t ro = (size_t)i * M;
    #pragma unroll
    for (int n = 0; n < 4; ++n) {
      int jb = bcol + wn * 64 + n * 16 + fq * 4;
      float4 e;
      e.x = exp2f(fminf(fmaf(m2gl2, acc[m][n][0], -(gxs + gys[n].x)), 0.f));
      e.y = exp2f(fminf(fmaf(m2gl2, acc[m][n][1], -(gxs + gys[n].y)), 0.f));
      e.z = exp2f(fminf(fmaf(m2gl2, acc[m][n][2], -(gxs + gys[n].z)), 0.f));
      e.w = exp2f(fminf(fmaf(m2gl2, acc[m][n][3], -(gxs + gys[n].w)), 0.f));
      *reinterpret_cast<float4*>(&out[ro + jb]) = e;
    }
  }
}

// ---------------------------------------------------------------------------
// Fallback: fp32 LDS-tiled, slow but correct for odd shapes.
// ---------------------------------------------------------------------------
__global__ __launch_bounds__(256) void rbf_naive(
    const float* __restrict__ x, const float* __restrict__ y,
    const float* __restrict__ gptr, float* __restrict__ out,
    int N, int M, int D) {
  __shared__ float xs[16][17];
  __shared__ float ys[16][17];
  int nbn = M / 16;
  int brow = (blockIdx.x / nbn) * 16;
  int bcol = (blockIdx.x % nbn) * 16;
  int ti = threadIdx.x >> 4, tj = threadIdx.x & 15;
  float dacc = 0.f, xacc = 0.f, yacc = 0.f;
  for (int k0 = 0; k0 < D; k0 += 16) {
    xs[ti][tj] = x[(size_t)(brow + ti) * D + k0 + tj];
    ys[ti][tj] = y[(size_t)(bcol + ti) * D + k0 + tj];
    __syncthreads();
    #pragma unroll
    for (int kk = 0; kk < 16; ++kk) {
      float xv = xs[ti][kk], yv = ys[tj][kk];
      dacc += xv * yv;
      xacc += xv * xv;
      yacc += yv * yv;
    }
    __syncthreads();
  }
  float gamma = gptr[0];
  float d2 = fmaxf(xacc + yacc - 2.f * dacc, 0.f);
  out[(size_t)(brow + ti) * M + (bcol + tj)] = __expf(-gamma * d2);
}

// ---------------------------------------------------------------------------
extern "C" void kernel_launch(void* const* d_in, const int* in_sizes, int n_in,
                              void* d_out, int out_size, void* d_ws,
                              size_t ws_size, hipStream_t stream) {
  const float* x = (const float*)d_in[0];
  const float* y = (const float*)d_in[1];
  const float* g = (const float*)d_in[2];
  float* out = (float*)d_out;

  const int D = 512;
  const int N = in_sizes[0] / D;
  const int M = in_sizes[1] / D;

  size_t need = (size_t)(N + M) * D * sizeof(u16) + (size_t)(N + M) * sizeof(float);
  bool shapes_ok = (N % BM == 0) && (M % BN == 0) && (D % BK == 0) && (D / BK >= 2);

  if (ws_size >= need && shapes_ok) {
    u16* xb = (u16*)d_ws;
    u16* yb = xb + (size_t)N * D;
    float* xsq = (float*)(yb + (size_t)M * D);
    float* ysq = xsq + N;

    rbf_prep<<<N + M, 128, 0, stream>>>(x, y, xb, yb, xsq, ysq, N, M, D);
    int nwg = (N / BM) * (M / BN);
    rbf_gemm<<<nwg, 512, 0, stream>>>(xb, yb, xsq, ysq, g, out, N, M, D);
  } else {
    rbf_naive<<<(N / 16) * (M / 16), 256, 0, stream>>>(x, y, g, out, N, M, D);
  }
}

// Round 9
// 117.366 us; speedup vs baseline: 1.1031x; 1.1031x over previous
//
#include <hip/hip_runtime.h>
#include <hip/hip_bf16.h>

typedef unsigned short u16;
typedef __attribute__((ext_vector_type(8))) short bf16x8;
typedef __attribute__((ext_vector_type(4))) float f32x4;

typedef const __attribute__((address_space(1))) void gvoid_t;
typedef __attribute__((address_space(3))) void lvoid_t;

__device__ __forceinline__ void gload_lds16(const void* g, void* l) {
  __builtin_amdgcn_global_load_lds((gvoid_t*)g, (lvoid_t*)l, 16, 0, 0);
}

__device__ __forceinline__ u16 f2bf(float f) {
  union { float f; unsigned u; } a;
  a.f = f;
  unsigned r = (a.u + 0x7FFFu + ((a.u >> 16) & 1u)) >> 16;  // RN-even
  return (u16)r;
}

// ---------------------------------------------------------------------------
// Prep: fp32 -> bf16 copies of x and y, plus per-row sum of squares.
// ---------------------------------------------------------------------------
__global__ __launch_bounds__(128) void rbf_prep(
    const float* __restrict__ x, const float* __restrict__ y,
    u16* __restrict__ xb, u16* __restrict__ yb,
    float* __restrict__ xsq, float* __restrict__ ysq,
    int N, int M, int D) {
  int row = blockIdx.x;
  const float* src;
  u16* dst;
  float* sq;
  if (row < N) {
    src = x + (size_t)row * D;
    dst = xb + (size_t)row * D;
    sq = xsq + row;
  } else {
    int r = row - N;
    src = y + (size_t)r * D;
    dst = yb + (size_t)r * D;
    sq = ysq + r;
  }
  int t = threadIdx.x;
  float4 v = reinterpret_cast<const float4*>(src)[t];
  float s = v.x * v.x + v.y * v.y + v.z * v.z + v.w * v.w;
  ushort4 o;
  o.x = f2bf(v.x);
  o.y = f2bf(v.y);
  o.z = f2bf(v.z);
  o.w = f2bf(v.w);
  reinterpret_cast<ushort4*>(dst)[t] = o;
  #pragma unroll
  for (int off = 32; off > 0; off >>= 1) s += __shfl_down(s, off, 64);
  __shared__ float red[2];
  if ((t & 63) == 0) red[t >> 6] = s;
  __syncthreads();
  if (t == 0) sq[0] = red[0] + red[1];
}

// ---------------------------------------------------------------------------
// R9 = R5 (best, 112.7 us) + NON-TEMPORAL output stores (single change).
// Rationale: output stream (268 MB fp32) churns the whole L2/L3 every pass,
// evicting the 16 MB input panels (R6 counters: ~70 MB HBM re-FETCH per
// replay). Evicted panels => staging at HBM latency ~900cy, which the
// 1-tile-ahead vmcnt pipeline (sized for L2 ~200-300cy) cannot hide =>
// the flat latency-bound profile across all schedule variants.
// nt-stores keep out of the caches; inputs stay resident; staging hits L2.
//
// Structure (R5, verified): 128x128 tile, BK=64, 4 waves (2Mx2N), LDS
// 64 KiB dbuf -> 2 blocks/CU. 3-bit chunk^=(row&7) swizzle both sides.
// Counted vmcnt(8). Swapped MFMA operands -> D[j][i] -> float4 out stores.
// Column-band supertile. exp2-fused epilogue.
// ---------------------------------------------------------------------------
#define BM 128
#define BN 128
#define BK 64

__global__ __launch_bounds__(256, 2) void rbf_gemm(
    const u16* __restrict__ xb, const u16* __restrict__ yb,
    const float* __restrict__ xsq, const float* __restrict__ ysq,
    const float* __restrict__ gptr, float* __restrict__ out,
    int N, int M, int D) {
  __shared__ u16 lds[2][2][BM * BK];  // 64 KiB

  int bid = blockIdx.x;
  int nbr = N / BM, nbc = M / BN;
  int trow, tcol;
  if (nbr == 64 && nbc == 64) {
    // XCD x owns tile-columns x*8..x*8+7, walked in 8x8-tile regions
    // (column-major inside a region): panels stay L2-resident per XCD.
    int xcd = bid & 7;
    int s = bid >> 3;        // 0..511
    int gr = s >> 6;         // region row 0..7
    int q = s & 63;          // within-region, column-major
    trow = gr * 8 + (q & 7);
    tcol = xcd * 8 + (q >> 3);
  } else {
    int cpx = gridDim.x >> 3;
    int swz = (bid & 7) * cpx + (bid >> 3);
    trow = swz / nbc;
    tcol = swz % nbc;
  }
  int brow = trow * BM;
  int bcol = tcol * BN;

  int tid = threadIdx.x;
  int w = tid >> 6;       // wave 0..3
  int lane = tid & 63;
  int wm = w >> 1;        // 0..1 row half (64 rows)
  int wn = w & 1;         // 0..1 col half (64 cols)
  int fr = lane & 15;
  int fq = lane >> 4;

  // --- staging: wave w stages rows w*32..w*32+31 of A and B tiles ---
  int srow = lane >> 3;                        // 0..7
  int scol = ((lane & 7) ^ srow) * 8;          // inverse-swizzled source col
  const u16* xsrc = xb + (size_t)(brow + w * 32 + srow) * D + scol;
  const u16* ysrc = yb + (size_t)(bcol + w * 32 + srow) * D + scol;
  int sdst = w * 2048;  // 32 rows * 64 elems

  // --- fragment read offsets: chunk ^= (row&7) ---
  int cxor = (fr & 7) * 8;
  int colx0 = (fq * 8) ^ cxor;        // kk=0
  int colx1 = (32 + fq * 8) ^ cxor;   // kk=1
  int arow0 = (wm * 64 + fr) * 64;
  int brow0 = (wn * 64 + fr) * 64;

  f32x4 acc[4][4];
  #pragma unroll
  for (int m = 0; m < 4; ++m)
    #pragma unroll
    for (int n = 0; n < 4; ++n)
      acc[m][n] = (f32x4){0.f, 0.f, 0.f, 0.f};

  auto stage = [&](int kt, int b) {
    const u16* xs = xsrc + kt * 64;
    const u16* ys = ysrc + kt * 64;
    u16* la = &lds[b][0][sdst];
    u16* lb = &lds[b][1][sdst];
    #pragma unroll
    for (int i = 0; i < 4; ++i)
      gload_lds16(xs + (size_t)i * 8 * D, la + i * 512);
    #pragma unroll
    for (int i = 0; i < 4; ++i)
      gload_lds16(ys + (size_t)i * 8 * D, lb + i * 512);
  };

  int nkt = D >> 6;  // 8
  stage(0, 0);
  stage(1, 1);
  for (int t = 0; t < nkt; ++t) {
    int b = t & 1;
    // my 8 loads of tile t landed (8 of tile t+1 stay in flight)
    if (t + 1 < nkt)
      asm volatile("s_waitcnt vmcnt(8)" ::: "memory");
    else
      asm volatile("s_waitcnt vmcnt(0)" ::: "memory");
    __builtin_amdgcn_sched_barrier(0);
    __builtin_amdgcn_s_barrier();  // all waves' tile-t data visible
    __builtin_amdgcn_sched_barrier(0);

    const u16* A = &lds[b][0][0];
    const u16* B = &lds[b][1][0];
    bf16x8 af[4][2], bf[4][2];
    #pragma unroll
    for (int m = 0; m < 4; ++m) {
      af[m][0] = *(const bf16x8*)&A[arow0 + m * 1024 + colx0];
      af[m][1] = *(const bf16x8*)&A[arow0 + m * 1024 + colx1];
    }
    #pragma unroll
    for (int n = 0; n < 4; ++n) {
      bf[n][0] = *(const bf16x8*)&B[brow0 + n * 1024 + colx0];
      bf[n][1] = *(const bf16x8*)&B[brow0 + n * 1024 + colx1];
    }

    // Swapped operands: D[j][i], j = fq*4 + r, i = fr.
    __builtin_amdgcn_s_setprio(1);
    #pragma unroll
    for (int m = 0; m < 4; ++m)
      #pragma unroll
      for (int n = 0; n < 4; ++n) {
        acc[m][n] = __builtin_amdgcn_mfma_f32_16x16x32_bf16(
            bf[n][0], af[m][0], acc[m][n], 0, 0, 0);
        acc[m][n] = __builtin_amdgcn_mfma_f32_16x16x32_bf16(
            bf[n][1], af[m][1], acc[m][n], 0, 0, 0);
      }
    __builtin_amdgcn_s_setprio(0);

    // my ds_reads of buf b done before anyone re-stages into it
    asm volatile("s_waitcnt lgkmcnt(0)" ::: "memory");
    __builtin_amdgcn_sched_barrier(0);
    __builtin_amdgcn_s_barrier();
    __builtin_amdgcn_sched_barrier(0);
    if (t + 2 < nkt) stage(t + 2, b);
  }

  // Epilogue: out = exp2(2*gl2*acc - gl2*|x|^2 - gl2*|y|^2), clamped <= 2^0.
  // NON-TEMPORAL stores: out is write-once; keep it out of L2/L3 so the
  // input panels stay cache-resident for the staging loads.
  float gl2 = gptr[0] * 1.44269504088896f;  // gamma * log2(e)
  float m2gl2 = 2.0f * gl2;
  float4 gys[4];
  #pragma unroll
  for (int n = 0; n < 4; ++n) {
    float4 t4 = *reinterpret_cast<const float4*>(
        &ysq[bcol + wn * 64 + n * 16 + fq * 4]);
    gys[n].x = gl2 * t4.x;
    gys[n].y = gl2 * t4.y;
    gys[n].z = gl2 * t4.z;
    gys[n].w = gl2 * t4.w;
  }
  #pragma unroll
  for (int m = 0; m < 4; ++m) {
    int i = brow + wm * 64 + m * 16 + fr;
    float gxs = gl2 * xsq[i];
    size_t ro = (size_t)i * M;
    #pragma unroll
    for (int n = 0; n < 4; ++n) {
      int jb = bcol + wn * 64 + n * 16 + fq * 4;
      f32x4 e;
      e[0] = exp2f(fminf(fmaf(m2gl2, acc[m][n][0], -(gxs + gys[n].x)), 0.f));
      e[1] = exp2f(fminf(fmaf(m2gl2, acc[m][n][1], -(gxs + gys[n].y)), 0.f));
      e[2] = exp2f(fminf(fmaf(m2gl2, acc[m][n][2], -(gxs + gys[n].z)), 0.f));
      e[3] = exp2f(fminf(fmaf(m2gl2, acc[m][n][3], -(gxs + gys[n].w)), 0.f));
      __builtin_nontemporal_store(e, reinterpret_cast<f32x4*>(&out[ro + jb]));
    }
  }
}

// ---------------------------------------------------------------------------
// Fallback: fp32 LDS-tiled, slow but correct for odd shapes.
// ---------------------------------------------------------------------------
__global__ __launch_bounds__(256) void rbf_naive(
    const float* __restrict__ x, const float* __restrict__ y,
    const float* __restrict__ gptr, float* __restrict__ out,
    int N, int M, int D) {
  __shared__ float xs[16][17];
  __shared__ float ys[16][17];
  int nbn = M / 16;
  int brow = (blockIdx.x / nbn) * 16;
  int bcol = (blockIdx.x % nbn) * 16;
  int ti = threadIdx.x >> 4, tj = threadIdx.x & 15;
  float dacc = 0.f, xacc = 0.f, yacc = 0.f;
  for (int k0 = 0; k0 < D; k0 += 16) {
    xs[ti][tj] = x[(size_t)(brow + ti) * D + k0 + tj];
    ys[ti][tj] = y[(size_t)(bcol + ti) * D + k0 + tj];
    __syncthreads();
    #pragma unroll
    for (int kk = 0; kk < 16; ++kk) {
      float xv = xs[ti][kk], yv = ys[tj][kk];
      dacc += xv * yv;
      xacc += xv * xv;
      yacc += yv * yv;
    }
    __syncthreads();
  }
  float gamma = gptr[0];
  float d2 = fmaxf(xacc + yacc - 2.f * dacc, 0.f);
  out[(size_t)(brow + ti) * M + (bcol + tj)] = __expf(-gamma * d2);
}

// ---------------------------------------------------------------------------
extern "C" void kernel_launch(void* const* d_in, const int* in_sizes, int n_in,
                              void* d_out, int out_size, void* d_ws,
                              size_t ws_size, hipStream_t stream) {
  const float* x = (const float*)d_in[0];
  const float* y = (const float*)d_in[1];
  const float* g = (const float*)d_in[2];
  float* out = (float*)d_out;

  const int D = 512;
  const int N = in_sizes[0] / D;
  const int M = in_sizes[1] / D;

  size_t need = (size_t)(N + M) * D * sizeof(u16) + (size_t)(N + M) * sizeof(float);
  bool shapes_ok = (N % BM == 0) && (M % BN == 0) && (D % BK == 0) && (D / BK >= 2);

  if (ws_size >= need && shapes_ok) {
    u16* xb = (u16*)d_ws;
    u16* yb = xb + (size_t)N * D;
    float* xsq = (float*)(yb + (size_t)M * D);
    float* ysq = xsq + N;

    rbf_prep<<<N + M, 128, 0, stream>>>(x, y, xb, yb, xsq, ysq, N, M, D);
    int nwg = (N / BM) * (M / BN);
    rbf_gemm<<<nwg, 256, 0, stream>>>(xb, yb, xsq, ysq, g, out, N, M, D);
  } else {
    rbf_naive<<<(N / 16) * (M / 16), 256, 0, stream>>>(x, y, g, out, N, M, D);
  }
}